// Round 3
// baseline (93.494 us; speedup 1.0000x reference)
//
#include <hip/hip_runtime.h>

// Depth-4 path signature, B=128, L=128, C=12, fp32.
// Round 8: MEASUREMENT ROUND. Kernel reverted to the best-measured variant
// (round-6 fused kernel, 73.25us): 448 threads, k-pairs, LDS-broadcast w,
// no software pipeline. The ONLY change: kernel_launch enqueues the SAME
// kernel TWICE with identical args. The second launch recomputes and
// rewrites byte-identical outputs (pure function of input), so correctness
// is unaffected. dur_delta vs 73.25us = exactly one sig execution + ~1-2us
// launch gap -- this discriminates H1 (sig ~30us: loop stall-dominated,
// keep optimizing) from H2 (sig ~10us: harness fill/reset floor, declare
// roofline). Fill-duration noise (+-2us) cannot fake a 20us separation.

#define NC    12
#define NPTS  128
#define NSTEP 128            // 127 real increments + 1 zero pad (identity)
#define OUT_PER_B 22620      // 12 + 144 + 1728 + 20736
#define BT 448               // 432 active = 6(i) * 12(j) * 6(k-pairs)
#define PADQ 33              // float4 row stride in transposed LDS table

__global__ __launch_bounds__(BT)
void sig_kernel(const float* __restrict__ path, float* __restrict__ out) {
    const int bid = blockIdx.x;
    const int b  = bid >> 1;
    const int ih = bid & 1;
    const int t  = threadIdx.x;

    __shared__ __align__(16) float  P[NPTS * NC];     // 6144 B staged path
    __shared__ __align__(16) float  W[NSTEP * NC];    // 6144 B row-major [s][c]
    __shared__ __align__(16) float4 DT4[NC * PADQ];   // 6336 B transposed [c][sq]

    // ---- stage path, coalesced (384 float4 = 6 KB) ----
    const float* pb = path + (size_t)b * (NPTS * NC);
    if (t < 384) ((float4*)P)[t] = ((const float4*)pb)[t];
    __syncthreads();

    // ---- increments into both LDS layouts (one-time) ----
    if (t < 384) {
        const int c  = t >> 5;        // 0..11
        const int sq = t & 31;        // 0..31
        float d[4];
        #pragma unroll
        for (int e = 0; e < 4; ++e) {
            const int s = 4 * sq + e;
            d[e] = (s < NPTS - 1) ? (P[(s + 1) * NC + c] - P[s * NC + c]) : 0.f;
            W[s * NC + c] = d[e];
        }
        DT4[c * PADQ + sq] = make_float4(d[0], d[1], d[2], d[3]);
    }
    __syncthreads();

    // ---- index map (pad threads duplicate work; stores guarded later) ----
    const int ta  = (t < 432) ? t : (t - 432);
    const int il  = ta / 72;
    const int rem = ta - il * 72;
    const int j   = rem / 6;
    const int kh  = rem - j * 6;
    const int i   = ih * 6 + il;
    const int k0  = kh * 2;

    float acc0[12], acc1[12];
    #pragma unroll
    for (int l = 0; l < 12; ++l) { acc0[l] = 0.f; acc1[l] = 0.f; }
    float s3a = 0.f, s3b = 0.f, s2 = 0.f, s1 = 0.f;

    const float4* wt   = (const float4*)W;        // 12 float4 per sq group
    const float4* dti  = &DT4[i * PADQ];
    const float4* dtj  = &DT4[j * PADQ];
    const float4* dtka = &DT4[k0 * PADQ];
    const float4* dtkb = &DT4[(k0 + 1) * PADQ];

    for (int sq = 0; sq < NSTEP / 4; ++sq) {
        // block-uniform 48 increments for these 4 steps: LDS broadcast reads
        float4 wq[12];
        #pragma unroll
        for (int q = 0; q < 12; ++q) wq[q] = wt[sq * 12 + q];

        // per-thread transposed reads (<=2-way conflict = free)
        float4 di4  = dti[sq];
        float4 dj4  = dtj[sq];
        float4 dka4 = dtka[sq];
        float4 dkb4 = dtkb[sq];

        #pragma unroll
        for (int u = 0; u < 4; ++u) {
            const float di  = (&di4.x)[u];
            const float dj  = (&dj4.x)[u];
            const float dka = (&dka4.x)[u];
            const float dkb = (&dkb4.x)[u];

            // Horner-factored Chen step (identical arithmetic to R2..R7)
            float A4  = (s1 + 0.25f * di) * (1.f / 3.f);
            float B4  = (s2 + dj * A4) * 0.5f;
            float C3a = s3a + dka * B4;
            float C3b = s3b + dkb * B4;

            #pragma unroll
            for (int l = 0; l < 12; ++l) {
                const float wl = (&wq[3 * u + (l >> 2)].x)[l & 3];
                acc0[l] += C3a * wl;
                acc1[l] += C3b * wl;
            }

            float A3 = (s1 + di * (1.f / 3.f)) * 0.5f;
            float C2 = s2 + dj * A3;
            s3a += dka * C2;
            s3b += dkb * C2;
            s2  += dj * (s1 + 0.5f * di);
            s1  += di;
        }
    }

    if (t < 432) {
        float* ob = out + (size_t)b * OUT_PER_B;
        if (j == 0 && kh == 0) ob[i] = s1;                 // level 1
        if (kh == 0) ob[12 + i * 12 + j] = s2;             // level 2
        const int ijk = (i * 12 + j) * 12 + k0;
        ob[156 + ijk]     = s3a;                           // level 3
        ob[156 + ijk + 1] = s3b;
        float4* o4 = (float4*)(ob + 1884 + (size_t)ijk * 12);  // level 4, 96B
        o4[0] = make_float4(acc0[0], acc0[1], acc0[2],  acc0[3]);
        o4[1] = make_float4(acc0[4], acc0[5], acc0[6],  acc0[7]);
        o4[2] = make_float4(acc0[8], acc0[9], acc0[10], acc0[11]);
        o4[3] = make_float4(acc1[0], acc1[1], acc1[2],  acc1[3]);
        o4[4] = make_float4(acc1[4], acc1[5], acc1[6],  acc1[7]);
        o4[5] = make_float4(acc1[8], acc1[9], acc1[10], acc1[11]);
    }
}

extern "C" void kernel_launch(void* const* d_in, const int* in_sizes, int n_in,
                              void* d_out, int out_size, void* d_ws, size_t ws_size,
                              hipStream_t stream) {
    const float* path = (const float*)d_in[0];
    float* out = (float*)d_out;
    const int nbatch = in_sizes[0] / (NPTS * NC);   // = 128

    // Launch TWICE (identical args): second launch writes identical values.
    // dur delta vs the single-launch round = one true sig execution time.
    sig_kernel<<<nbatch * 2, BT, 0, stream>>>(path, out);
    sig_kernel<<<nbatch * 2, BT, 0, stream>>>(path, out);
}

// Round 4
// 78.401 us; speedup vs baseline: 1.1925x; 1.1925x over previous
//
#include <hip/hip_runtime.h>

// Depth-4 path signature, B=128, L=128, C=12, fp32.
// Round 9: R8 measurement showed one sig execution ~= 20us (double-launch
// delta), i.e. ~1500 cyc/iter/CU vs a 567-cyc VALU issue bound. The gap is
// the 12 broadcast ds_read_b128/iter issued redundantly by ALL 7 waves
// (~1100+ LDS-pipe cyc/CU/iter) plus mixed lgkm serialization.
// Fix (R5's idea done right, fused): s_load the block-uniform path rows
// directly from the READ-ONLY input buffer (host-written -> no cross-XCD
// dirty-line penalty, no prep kernel) into SGPRs each iteration, and
// reconstruct the 48 broadcast increments in VGPRs (~96 mov/sub VALU,
// 1-SGPR-per-VALU rule respected). Per-thread di/dj/dk stay as 4
// transposed ds_read_b128 (<=2-way conflicts, cheap). Increment values are
// bit-identical (same fp32 subtraction). Single launch restored.

#define NC    12
#define NPTS  128
#define OUT_PER_B 22620      // 12 + 144 + 1728 + 20736
#define BT 448               // 432 active = 6(i) * 12(j) * 6(k-pairs)
#define PADQ 33              // float4 row stride in transposed LDS table

typedef float vf16 __attribute__((ext_vector_type(16)));
typedef float vf8  __attribute__((ext_vector_type(8)));
typedef float vf4  __attribute__((ext_vector_type(4)));

// Compile-time-constant element pick from the 5 SGPR row vectors
// (e in [0,60): 60 floats = path rows 4sq .. 4sq+4, 12 ch each)
#define SGET(e) ((e) < 16 ? r0[(e)] : (e) < 32 ? r1[(e) - 16] : \
                 (e) < 48 ? r2[(e) - 32] : (e) < 56 ? r3a[(e) - 48] : r3b[(e) - 56])

// Chen step over 4 sub-steps; identical arithmetic to R2..R8.
// Uses locals: w[48], di4, dj4, dka4, dkb4, s1, s2, s3a, s3b, acc0, acc1.
#define COMPUTE() do {                                            \
        _Pragma("unroll")                                         \
        for (int u = 0; u < 4; ++u) {                             \
            const float di  = (&di4.x)[u];                        \
            const float dj  = (&dj4.x)[u];                        \
            const float dka = (&dka4.x)[u];                       \
            const float dkb = (&dkb4.x)[u];                       \
            float A4  = (s1 + 0.25f * di) * (1.f / 3.f);          \
            float B4  = (s2 + dj * A4) * 0.5f;                    \
            float C3a = s3a + dka * B4;                           \
            float C3b = s3b + dkb * B4;                           \
            _Pragma("unroll")                                     \
            for (int l = 0; l < 12; ++l) {                        \
                const float wl = w[12 * u + l];                   \
                acc0[l] += C3a * wl;                              \
                acc1[l] += C3b * wl;                              \
            }                                                     \
            float A3 = (s1 + di * (1.f / 3.f)) * 0.5f;            \
            float C2 = s2 + dj * A3;                              \
            s3a += dka * C2;                                      \
            s3b += dkb * C2;                                      \
            s2  += dj * (s1 + 0.5f * di);                         \
            s1  += di;                                            \
        }                                                         \
    } while (0)

__global__ __launch_bounds__(BT)
void sig_kernel(const float* __restrict__ path, float* __restrict__ out) {
    const int bid = blockIdx.x;
    const int b  = bid >> 1;
    const int ih = bid & 1;
    const int t  = threadIdx.x;

    __shared__ __align__(16) float  P[NPTS * NC];     // 6144 B staged path
    __shared__ __align__(16) float4 DT4[NC * PADQ];   // 6336 B transposed [c][sq]

    // ---- stage path, coalesced (384 float4 = 6 KB) ----
    const float* pb = path + (size_t)b * (NPTS * NC);
    if (t < 384) ((float4*)P)[t] = ((const float4*)pb)[t];
    __syncthreads();

    // ---- per-thread transposed increment table (one-time) ----
    if (t < 384) {
        const int c  = t >> 5;        // 0..11
        const int sq = t & 31;        // 0..31
        float d[4];
        #pragma unroll
        for (int e = 0; e < 4; ++e) {
            const int s = 4 * sq + e;
            d[e] = (s < NPTS - 1) ? (P[(s + 1) * NC + c] - P[s * NC + c]) : 0.f;
        }
        DT4[c * PADQ + sq] = make_float4(d[0], d[1], d[2], d[3]);
    }
    __syncthreads();

    // ---- index map (pad threads duplicate work; stores guarded later) ----
    const int ta  = (t < 432) ? t : (t - 432);
    const int il  = ta / 72;
    const int rem = ta - il * 72;
    const int j   = rem / 6;
    const int kh  = rem - j * 6;
    const int i   = ih * 6 + il;
    const int k0  = kh * 2;

    float acc0[12], acc1[12];
    #pragma unroll
    for (int l = 0; l < 12; ++l) { acc0[l] = 0.f; acc1[l] = 0.f; }
    float s3a = 0.f, s3b = 0.f, s2 = 0.f, s1 = 0.f;

    // Block-uniform base address of this batch's path rows, in an SGPR pair.
    unsigned long long base_u;
    {
        unsigned long long a = (unsigned long long)pb;
        unsigned int lo = __builtin_amdgcn_readfirstlane((unsigned int)a);
        unsigned int hi = __builtin_amdgcn_readfirstlane((unsigned int)(a >> 32));
        base_u = ((unsigned long long)hi << 32) | lo;
    }

    const float4* dti  = &DT4[i * PADQ];
    const float4* dtj  = &DT4[j * PADQ];
    const float4* dtka = &DT4[k0 * PADQ];
    const float4* dtkb = &DT4[(k0 + 1) * PADQ];

    for (int sq = 0; sq < 31; ++sq) {
        // per-thread transposed reads first (their latency overlaps s_load)
        float4 di4  = dti[sq];
        float4 dj4  = dtj[sq];
        float4 dka4 = dtka[sq];
        float4 dkb4 = dtkb[sq];

        // block-uniform path rows 4sq..4sq+4 (60 floats, 240 B) -> SGPRs.
        // Read-only input buffer: K$/L2-clean, no cross-XCD dirty lines.
        vf16 r0, r1, r2; vf8 r3a; vf4 r3b;
        {
            const float* wp = (const float*)(base_u + (unsigned long long)(sq * 192));
            asm volatile(
                "s_load_dwordx16 %0, %5, 0x0\n\t"
                "s_load_dwordx16 %1, %5, 0x40\n\t"
                "s_load_dwordx16 %2, %5, 0x80\n\t"
                "s_load_dwordx8  %3, %5, 0xc0\n\t"
                "s_load_dwordx4  %4, %5, 0xe0\n\t"
                "s_waitcnt lgkmcnt(0)"
                : "=&s"(r0), "=&s"(r1), "=&s"(r2), "=&s"(r3a), "=&s"(r3b)
                : "s"(wp));
        }

        // reconstruct the 48 broadcast increments in VGPRs (mov+sub;
        // v_sub_f32 takes 1 SGPR operand, compiler inserts movs for the rest)
        float w[48];
        #pragma unroll
        for (int u = 0; u < 4; ++u)
            #pragma unroll
            for (int c = 0; c < 12; ++c)
                w[12 * u + c] = SGET(12 * (u + 1) + c) - SGET(12 * u + c);

        COMPUTE();
    }

    // ---- peeled last iteration (sq=31): rows 124..127 only; step 127 is
    // the zero-pad identity increment (w3 = 0, DT4 row already 0). Avoids
    // the 64B out-of-bounds tail read on the last batch. ----
    {
        const int sq = 31;
        float4 di4  = dti[sq];
        float4 dj4  = dtj[sq];
        float4 dka4 = dtka[sq];
        float4 dkb4 = dtkb[sq];

        vf16 r0, r1, r2;
        vf8 r3a = {0.f}; vf4 r3b = {0.f};   // dummies for SGET's dead arms
        (void)r3a; (void)r3b;
        {
            const float* wp = (const float*)(base_u + (unsigned long long)(sq * 192));
            asm volatile(
                "s_load_dwordx16 %0, %3, 0x0\n\t"
                "s_load_dwordx16 %1, %3, 0x40\n\t"
                "s_load_dwordx16 %2, %3, 0x80\n\t"
                "s_waitcnt lgkmcnt(0)"
                : "=&s"(r0), "=&s"(r1), "=&s"(r2)
                : "s"(wp));
        }

        float w[48];
        #pragma unroll
        for (int u = 0; u < 3; ++u)
            #pragma unroll
            for (int c = 0; c < 12; ++c)
                w[12 * u + c] = SGET(12 * (u + 1) + c) - SGET(12 * u + c);
        #pragma unroll
        for (int c = 0; c < 12; ++c) w[36 + c] = 0.f;

        COMPUTE();
    }

    if (t < 432) {
        float* ob = out + (size_t)b * OUT_PER_B;
        if (j == 0 && kh == 0) ob[i] = s1;                 // level 1
        if (kh == 0) ob[12 + i * 12 + j] = s2;             // level 2
        const int ijk = (i * 12 + j) * 12 + k0;
        ob[156 + ijk]     = s3a;                           // level 3
        ob[156 + ijk + 1] = s3b;
        float4* o4 = (float4*)(ob + 1884 + (size_t)ijk * 12);  // level 4, 96B
        o4[0] = make_float4(acc0[0], acc0[1], acc0[2],  acc0[3]);
        o4[1] = make_float4(acc0[4], acc0[5], acc0[6],  acc0[7]);
        o4[2] = make_float4(acc0[8], acc0[9], acc0[10], acc0[11]);
        o4[3] = make_float4(acc1[0], acc1[1], acc1[2],  acc1[3]);
        o4[4] = make_float4(acc1[4], acc1[5], acc1[6],  acc1[7]);
        o4[5] = make_float4(acc1[8], acc1[9], acc1[10], acc1[11]);
    }
}

extern "C" void kernel_launch(void* const* d_in, const int* in_sizes, int n_in,
                              void* d_out, int out_size, void* d_ws, size_t ws_size,
                              hipStream_t stream) {
    const float* path = (const float*)d_in[0];
    float* out = (float*)d_out;
    const int nbatch = in_sizes[0] / (NPTS * NC);   // = 128

    sig_kernel<<<nbatch * 2, BT, 0, stream>>>(path, out);
}

// Round 5
// 77.701 us; speedup vs baseline: 1.2033x; 1.0090x over previous
//
#include <hip/hip_runtime.h>

// Depth-4 path signature, B=128, L=128, C=12, fp32.
// Round 10: R8 measured sig ~= 20us (~1500 cyc/iter/CU); model says the
// kernel is LDS-pipe-bound: 7 waves x 16 ds_read_b128 x ~12cyc ~= 1340
// cyc/iter/CU, and 12/16 reads per wave are broadcast w data (uniform
// address b128 = only 16 useful bytes). R9's scalar-pipe attempt lost to
// per-wave s_load redundancy + lgkmcnt(0) drains.
// Fix: move the broadcast REDISTRIBUTION to the VALU pipe:
//   - one ds_read_b64 per iter with per-lane addresses (lane l reads
//     W[48sq+2l]; 2-way bank aliasing = free) fetches all 48 w floats
//     of the 4-step group in a single full-width LDS transaction;
//   - 48 compile-time v_readlane_b32 broadcast them to SGPRs;
//   - level-4 FMAs become v_fmac_f32 vacc, s_w, vC3 (1 SGPR/VALU ok).
// Per-CU/iter: LDS 7x(1 b64 + 4 b128) ~380 cyc, VALU ~735 cyc -> ~2x faster
// main loop. 1-deep register prefetch of all 5 LDS loads hides ds latency
// at 1.75 waves/SIMD. Arithmetic & increment values bit-identical to R6.

#define NC    12
#define NPTS  128
#define NSTEP 128            // 127 real increments + 1 zero pad (identity)
#define OUT_PER_B 22620      // 12 + 144 + 1728 + 20736
#define BT 448               // 432 active = 6(i) * 12(j) * 6(k-pairs)
#define PADQ 33              // float4 row stride in transposed LDS table
#define WPAD 1552            // 1536 + 16 so lanes 24..31 stay in-bounds

__device__ __forceinline__ float rdlane(float v, int l) {
    return __int_as_float(__builtin_amdgcn_readlane(__float_as_int(v), l));
}

__global__ __launch_bounds__(BT)
void sig_kernel(const float* __restrict__ path, float* __restrict__ out) {
    const int bid = blockIdx.x;
    const int b  = bid >> 1;
    const int ih = bid & 1;
    const int t  = threadIdx.x;

    __shared__ __align__(16) float  P[NPTS * NC];     // 6144 B staged path
    __shared__ __align__(16) float  W[WPAD];          // row-major [s][c] + pad
    __shared__ __align__(16) float4 DT4[NC * PADQ];   // 6336 B transposed [c][sq]

    // ---- stage path, coalesced (384 float4 = 6 KB) ----
    const float* pb = path + (size_t)b * (NPTS * NC);
    if (t < 384) ((float4*)P)[t] = ((const float4*)pb)[t];
    __syncthreads();

    // ---- increments into both LDS layouts (one-time) ----
    if (t < 384) {
        const int c  = t >> 5;        // 0..11
        const int sq = t & 31;        // 0..31
        float d[4];
        #pragma unroll
        for (int e = 0; e < 4; ++e) {
            const int s = 4 * sq + e;
            d[e] = (s < NPTS - 1) ? (P[(s + 1) * NC + c] - P[s * NC + c]) : 0.f;
            W[s * NC + c] = d[e];
        }
        DT4[c * PADQ + sq] = make_float4(d[0], d[1], d[2], d[3]);
    }
    __syncthreads();

    // ---- index map (pad threads duplicate work; stores guarded later) ----
    const int ta  = (t < 432) ? t : (t - 432);
    const int il  = ta / 72;
    const int rem = ta - il * 72;
    const int j   = rem / 6;
    const int kh  = rem - j * 6;
    const int i   = ih * 6 + il;
    const int k0  = kh * 2;

    float acc0[12], acc1[12];
    #pragma unroll
    for (int l = 0; l < 12; ++l) { acc0[l] = 0.f; acc1[l] = 0.f; }
    float s3a = 0.f, s3b = 0.f, s2 = 0.f, s1 = 0.f;

    const float4* dti  = &DT4[i * PADQ];
    const float4* dtj  = &DT4[j * PADQ];
    const float4* dtka = &DT4[k0 * PADQ];
    const float4* dtkb = &DT4[(k0 + 1) * PADQ];

    // per-lane pointer into W: lane l of each wave holds floats
    // {W[48sq+2l], W[48sq+2l+1]} after each b64 read (2-way alias = free)
    const float* wbase = W + 2 * (t & 31);

    // ---- 1-deep prefetch registers ----
    float2 wv  = *(const float2*)(wbase);
    float4 pi  = dti[0],  pj = dtj[0],  pa = dtka[0],  pk = dtkb[0];

    for (int sq = 0; sq < 32; ++sq) {
        // prefetch next iteration's 5 LDS loads (clamped; sq=31 redundant)
        const int nx = (sq < 31) ? sq + 1 : 31;
        float2 wvn = *(const float2*)(wbase + 48 * nx);
        float4 ni  = dti[nx], nj = dtj[nx], na = dtka[nx], nk = dtkb[nx];

        #pragma unroll
        for (int u = 0; u < 4; ++u) {
            const float di  = (&pi.x)[u];
            const float dj  = (&pj.x)[u];
            const float dka = (&pa.x)[u];
            const float dkb = (&pk.x)[u];

            // Horner-factored Chen step (identical arithmetic to R2..R9)
            float A4  = (s1 + 0.25f * di) * (1.f / 3.f);
            float B4  = (s2 + dj * A4) * 0.5f;
            float C3a = s3a + dka * B4;
            float C3b = s3b + dkb * B4;

            #pragma unroll
            for (int l = 0; l < 12; ++l) {
                const int e = 12 * u + l;               // compile-time
                const float wl = (e & 1) ? rdlane(wv.y, e >> 1)
                                         : rdlane(wv.x, e >> 1);
                acc0[l] += C3a * wl;
                acc1[l] += C3b * wl;
            }

            float A3 = (s1 + di * (1.f / 3.f)) * 0.5f;
            float C2 = s2 + dj * A3;
            s3a += dka * C2;
            s3b += dkb * C2;
            s2  += dj * (s1 + 0.5f * di);
            s1  += di;
        }

        wv = wvn; pi = ni; pj = nj; pa = na; pk = nk;
    }

    if (t < 432) {
        float* ob = out + (size_t)b * OUT_PER_B;
        if (j == 0 && kh == 0) ob[i] = s1;                 // level 1
        if (kh == 0) ob[12 + i * 12 + j] = s2;             // level 2
        const int ijk = (i * 12 + j) * 12 + k0;
        ob[156 + ijk]     = s3a;                           // level 3
        ob[156 + ijk + 1] = s3b;
        float4* o4 = (float4*)(ob + 1884 + (size_t)ijk * 12);  // level 4, 96B
        o4[0] = make_float4(acc0[0], acc0[1], acc0[2],  acc0[3]);
        o4[1] = make_float4(acc0[4], acc0[5], acc0[6],  acc0[7]);
        o4[2] = make_float4(acc0[8], acc0[9], acc0[10], acc0[11]);
        o4[3] = make_float4(acc1[0], acc1[1], acc1[2],  acc1[3]);
        o4[4] = make_float4(acc1[4], acc1[5], acc1[6],  acc1[7]);
        o4[5] = make_float4(acc1[8], acc1[9], acc1[10], acc1[11]);
    }
}

extern "C" void kernel_launch(void* const* d_in, const int* in_sizes, int n_in,
                              void* d_out, int out_size, void* d_ws, size_t ws_size,
                              hipStream_t stream) {
    const float* path = (const float*)d_in[0];
    float* out = (float*)d_out;
    const int nbatch = in_sizes[0] / (NPTS * NC);   // = 128

    sig_kernel<<<nbatch * 2, BT, 0, stream>>>(path, out);
}

// Round 6
// 75.938 us; speedup vs baseline: 1.2312x; 1.0232x over previous
//
#include <hip/hip_runtime.h>

// Depth-4 path signature, B=128, L=128, C=12, fp32.
// Round 11: synthesis of the R1-R5 evidence. LDS traffic does NOT
// correlate with runtime (R1 112 b128/CU/iter = 20us; R2 72 = 23.5us;
// R5 35 = 24.5us) -> not LDS-throughput-bound; uniform-address b128
// broadcast is cheap. R4/R5 scalar-side attempts lose to per-wave s_load
// redundancy / v_readlane->SGPR-use hazards. R2's pipeline lost because it
// also halved occupancy (1 wave/SIMD). Remaining identified stall: R1
// loads and consumes in the SAME iteration -> exposed ds_read latency
// every iter at 1.75 waves/SIMD.
// Change (ONE variable vs R1): keep 448 threads / k-pairs / 12 uniform
// wq b128 + 4 transposed b128 exactly as R1, add a 1-deep register
// double-buffer (unroll x2, A/B buffers): iteration n's compute hides
// iteration n+1's LDS latency. Arithmetic bit-identical to R1/R6.

#define NC    12
#define NPTS  128
#define NSTEP 128            // 127 real increments + 1 zero pad (identity)
#define OUT_PER_B 22620      // 12 + 144 + 1728 + 20736
#define BT 448               // 432 active = 6(i) * 12(j) * 6(k-pairs)
#define PADQ 33              // float4 row stride in transposed LDS table

__global__ __launch_bounds__(BT)
void sig_kernel(const float* __restrict__ path, float* __restrict__ out) {
    const int bid = blockIdx.x;
    const int b  = bid >> 1;
    const int ih = bid & 1;
    const int t  = threadIdx.x;

    __shared__ __align__(16) float  P[NPTS * NC];     // 6144 B staged path
    __shared__ __align__(16) float  W[NSTEP * NC];    // 6144 B row-major [s][c]
    __shared__ __align__(16) float4 DT4[NC * PADQ];   // 6336 B transposed [c][sq]

    // ---- stage path, coalesced (384 float4 = 6 KB) ----
    const float* pb = path + (size_t)b * (NPTS * NC);
    if (t < 384) ((float4*)P)[t] = ((const float4*)pb)[t];
    __syncthreads();

    // ---- increments into both LDS layouts (one-time) ----
    if (t < 384) {
        const int c  = t >> 5;        // 0..11
        const int sq = t & 31;        // 0..31
        float d[4];
        #pragma unroll
        for (int e = 0; e < 4; ++e) {
            const int s = 4 * sq + e;
            d[e] = (s < NPTS - 1) ? (P[(s + 1) * NC + c] - P[s * NC + c]) : 0.f;
            W[s * NC + c] = d[e];
        }
        DT4[c * PADQ + sq] = make_float4(d[0], d[1], d[2], d[3]);
    }
    __syncthreads();

    // ---- index map (pad threads duplicate work; stores guarded later) ----
    const int ta  = (t < 432) ? t : (t - 432);
    const int il  = ta / 72;
    const int rem = ta - il * 72;
    const int j   = rem / 6;
    const int kh  = rem - j * 6;
    const int i   = ih * 6 + il;
    const int k0  = kh * 2;

    float acc0[12], acc1[12];
    #pragma unroll
    for (int l = 0; l < 12; ++l) { acc0[l] = 0.f; acc1[l] = 0.f; }
    float s3a = 0.f, s3b = 0.f, s2 = 0.f, s1 = 0.f;

    const float4* wt   = (const float4*)W;        // 12 float4 per sq group
    const float4* dti  = &DT4[i * PADQ];
    const float4* dtj  = &DT4[j * PADQ];
    const float4* dtka = &DT4[k0 * PADQ];
    const float4* dtkb = &DT4[(k0 + 1) * PADQ];

    float4 wqA[12], wqB[12];          // uniform-address broadcast buffers
    float4 iA, jA, aA, bA;            // per-thread transposed buffers
    float4 iB, jB, aB, bB;

#define LOADA(S) do {                                             \
        _Pragma("unroll")                                         \
        for (int q = 0; q < 12; ++q) wqA[q] = wt[(S) * 12 + q];   \
        iA = dti[S]; jA = dtj[S]; aA = dtka[S]; bA = dtkb[S];     \
    } while (0)
#define LOADB(S) do {                                             \
        _Pragma("unroll")                                         \
        for (int q = 0; q < 12; ++q) wqB[q] = wt[(S) * 12 + q];   \
        iB = dti[S]; jB = dtj[S]; aB = dtka[S]; bB = dtkb[S];     \
    } while (0)

#define COMPUTE(WQ, DI, DJ, DA, DB) do {                          \
        _Pragma("unroll")                                         \
        for (int u = 0; u < 4; ++u) {                             \
            const float di  = (&DI.x)[u];                         \
            const float dj  = (&DJ.x)[u];                         \
            const float dka = (&DA.x)[u];                         \
            const float dkb = (&DB.x)[u];                         \
            float A4  = (s1 + 0.25f * di) * (1.f / 3.f);          \
            float B4  = (s2 + dj * A4) * 0.5f;                    \
            float C3a = s3a + dka * B4;                           \
            float C3b = s3b + dkb * B4;                           \
            _Pragma("unroll")                                     \
            for (int l = 0; l < 12; ++l) {                        \
                const float wl = (&WQ[3 * u + (l >> 2)].x)[l & 3];\
                acc0[l] += C3a * wl;                              \
                acc1[l] += C3b * wl;                              \
            }                                                     \
            float A3 = (s1 + di * (1.f / 3.f)) * 0.5f;            \
            float C2 = s2 + dj * A3;                              \
            s3a += dka * C2;                                      \
            s3b += dkb * C2;                                      \
            s2  += dj * (s1 + 0.5f * di);                         \
            s1  += di;                                            \
        }                                                         \
    } while (0)

    // ---- software-pipelined main loop (R1 structure + prefetch) ----
    LOADA(0);
    for (int sq = 0; sq < 32; sq += 2) {
        LOADB(sq + 1);
        COMPUTE(wqA, iA, jA, aA, bA);
        if (sq + 2 < 32) LOADA(sq + 2);
        COMPUTE(wqB, iB, jB, aB, bB);
    }

#undef LOADA
#undef LOADB
#undef COMPUTE

    if (t < 432) {
        float* ob = out + (size_t)b * OUT_PER_B;
        if (j == 0 && kh == 0) ob[i] = s1;                 // level 1
        if (kh == 0) ob[12 + i * 12 + j] = s2;             // level 2
        const int ijk = (i * 12 + j) * 12 + k0;
        ob[156 + ijk]     = s3a;                           // level 3
        ob[156 + ijk + 1] = s3b;
        float4* o4 = (float4*)(ob + 1884 + (size_t)ijk * 12);  // level 4, 96B
        o4[0] = make_float4(acc0[0], acc0[1], acc0[2],  acc0[3]);
        o4[1] = make_float4(acc0[4], acc0[5], acc0[6],  acc0[7]);
        o4[2] = make_float4(acc0[8], acc0[9], acc0[10], acc0[11]);
        o4[3] = make_float4(acc1[0], acc1[1], acc1[2],  acc1[3]);
        o4[4] = make_float4(acc1[4], acc1[5], acc1[6],  acc1[7]);
        o4[5] = make_float4(acc1[8], acc1[9], acc1[10], acc1[11]);
    }
}

extern "C" void kernel_launch(void* const* d_in, const int* in_sizes, int n_in,
                              void* d_out, int out_size, void* d_ws, size_t ws_size,
                              hipStream_t stream) {
    const float* path = (const float*)d_in[0];
    float* out = (float*)d_out;
    const int nbatch = in_sizes[0] / (NPTS * NC);   // = 128

    sig_kernel<<<nbatch * 2, BT, 0, stream>>>(path, out);
}